// Round 1
// 17924.152 us; speedup vs baseline: 1.0066x; 1.0066x over previous
//
#include <hip/hip_runtime.h>
#include <hip/hip_bf16.h>

// GRU T=512 B=64 IC=HC=512 L=2 — round 4.
// R1: 18.9us/barrier (threadfence = L2 wb/inv tag-walk).
// R2: 20.2us/barrier — RELEASE agent atomics STILL emit buffer_wbl2.
// R3: fully relaxed barrier: 17.4us/round. Fence-INVARIANT cost => the
//     constant is not cache maintenance. Remaining suspect: 64 same-line
//     atomic fetch_adds per round (cross-XCD RMWs serialize at the L3
//     atomic unit, ~200ns each ~= 13-16us) + two-hop release (arrive ->
//     leader -> gen store -> pollers).
// R4: all-report barrier. Each WG relaxed-stores its monotonic round to its
//     OWN flag (no RMW anywhere); wave0's 64 lanes poll all flags with one
//     coalesced load + __all ballot (single-hop release). Barriers are
//     per-layer: L0 never reads L1 data and y0seq is write-once, so L0 runs
//     ahead freely; L1 gates on L0's flags >= the round that wrote y0seq[s]
//     (odd r: need r; even r: need r-1). Ordering argument unchanged from
//     R3: __syncthreads drains vmcnt(0) so a WG's sc1 stores are at L3
//     before its flag store issues.

#define T_STEPS 512
#define BATCH   64
#define ICH     512
#define HCH     512
#define NL      2
#define M_TOT   (T_STEPS*BATCH)   // 32768
#define N1      (2*HCH)           // 1024
#define KCAT    (ICH+HCH)         // 1024
#define NWG     64
#define NTHR    512
#define FLG_STRIDE 8              // dwords between per-WG flags (32B)

using bf16x8  = __attribute__((ext_vector_type(8))) __bf16;
using floatx4 = __attribute__((ext_vector_type(4))) float;
using uint4v  = __attribute__((ext_vector_type(4))) unsigned int;

__device__ __forceinline__ unsigned short f2bf(float f) {
    unsigned int u = __builtin_bit_cast(unsigned int, f);
    u += 0x7FFFu + ((u >> 16) & 1u);          // RNE
    return (unsigned short)(u >> 16);
}
__device__ __forceinline__ float bf2f(unsigned short s) {
    unsigned int u = ((unsigned int)s) << 16;
    return __builtin_bit_cast(float, u);
}
__device__ __forceinline__ float sigmoidf_(float x) {
    return 1.0f / (1.0f + __expf(-x));
}
__device__ __forceinline__ floatx4 mfma_bf16(bf16x8 a, bf16x8 b, floatx4 c) {
    return __builtin_amdgcn_mfma_f32_16x16x32_bf16(a, b, c, 0, 0, 0);
}

// coherent (L2-bypassing, relaxed) accessors — no cache maintenance
__device__ __forceinline__ bf16x8 ld_frag_co(const unsigned short* p) {
    union { unsigned long long q[2]; bf16x8 v; } u;
    u.q[0] = __hip_atomic_load((const unsigned long long*)p,
                               __ATOMIC_RELAXED, __HIP_MEMORY_SCOPE_AGENT);
    u.q[1] = __hip_atomic_load(((const unsigned long long*)p) + 1,
                               __ATOMIC_RELAXED, __HIP_MEMORY_SCOPE_AGENT);
    return u.v;
}
__device__ __forceinline__ void st_word_co(unsigned short* p, unsigned int w) {
    __hip_atomic_store((unsigned int*)p, w, __ATOMIC_RELAXED, __HIP_MEMORY_SCOPE_AGENT);
}

// ---------------------------------------------------------------- prep
__global__ void prep_kernel(const float* __restrict__ x,
                            const float* __restrict__ W1,
                            const float* __restrict__ W2,
                            unsigned short* __restrict__ xb,
                            unsigned short* __restrict__ W1b,
                            unsigned short* __restrict__ W2b) {
    const int NX  = M_TOT*ICH;
    const int NW1 = NL*N1*KCAT;
    const int NW2 = NL*HCH*KCAT;
    const int total = NX + NW1 + NW2;
    for (int i = blockIdx.x*blockDim.x + threadIdx.x; i < total;
         i += gridDim.x*blockDim.x) {
        if (i < NX)           xb[i]         = f2bf(x[i]);
        else if (i < NX+NW1)  W1b[i-NX]     = f2bf(W1[i-NX]);
        else                  W2b[i-NX-NW1] = f2bf(W2[i-NX-NW1]);
    }
}

// ---------------------------------------------------------------- xproj (layer 0 only)
#define XP_LDP 40
__global__ void __launch_bounds__(256)
xproj_kernel(int layer,
             const unsigned short* __restrict__ Ab,
             const unsigned short* __restrict__ W1b,
             const unsigned short* __restrict__ W2b,
             const float* __restrict__ b1,
             const float* __restrict__ b2,
             unsigned short* __restrict__ X1p,
             unsigned short* __restrict__ X2p) {
    __shared__ unsigned short Ash[128*XP_LDP];
    __shared__ unsigned short Bsh[128*XP_LDP];
    const int nb = blockIdx.x;
    const int mb = blockIdx.y;
    const int tid = threadIdx.x;
    const int lane = tid & 63;
    const int wv = tid >> 6;
    const int wr = (wv >> 1) * 64;
    const int wc = (wv & 1) * 64;
    const int rfrag = lane & 15;
    const int koff = (lane >> 4) * 8;
    const int n0 = nb * 128;

    floatx4 acc[4][4];
    #pragma unroll
    for (int i=0;i<4;i++)
        #pragma unroll
        for (int j=0;j<4;j++) acc[i][j] = (floatx4)(0.0f);

    for (int kc = 0; kc < ICH/32; ++kc) {
        #pragma unroll
        for (int c = 0; c < 2; ++c) {
            int chunk = tid + c*256;
            int row = chunk >> 2;
            int c8  = (chunk & 3) * 8;
            *reinterpret_cast<uint4v*>(&Ash[row*XP_LDP + c8]) =
                *reinterpret_cast<const uint4v*>(&Ab[(size_t)(mb*128 + row)*ICH + kc*32 + c8]);
            int nrow = n0 + row;
            const unsigned short* bsrc = (nrow < N1)
                ? (W1b + (size_t)(layer*N1 + nrow)*KCAT + kc*32 + c8)
                : (W2b + (size_t)(layer*HCH + (nrow - N1))*KCAT + kc*32 + c8);
            *reinterpret_cast<uint4v*>(&Bsh[row*XP_LDP + c8]) =
                *reinterpret_cast<const uint4v*>(bsrc);
        }
        __syncthreads();
        bf16x8 af[4], bfr[4];
        #pragma unroll
        for (int mt=0; mt<4; ++mt)
            af[mt] = *reinterpret_cast<const bf16x8*>(&Ash[(wr + mt*16 + rfrag)*XP_LDP + koff]);
        #pragma unroll
        for (int nt=0; nt<4; ++nt)
            bfr[nt] = *reinterpret_cast<const bf16x8*>(&Bsh[(wc + nt*16 + rfrag)*XP_LDP + koff]);
        #pragma unroll
        for (int mt=0; mt<4; ++mt)
            #pragma unroll
            for (int nt=0; nt<4; ++nt)
                acc[mt][nt] = mfma_bf16(af[mt], bfr[nt], acc[mt][nt]);
        __syncthreads();
    }

    const int col0 = lane & 15;
    const int row0 = (lane >> 4) * 4;
    #pragma unroll
    for (int mt=0; mt<4; ++mt) {
        #pragma unroll
        for (int nt=0; nt<4; ++nt) {
            int n = n0 + wc + nt*16 + col0;
            #pragma unroll
            for (int r=0; r<4; ++r) {
                int m = mb*128 + wr + mt*16 + row0 + r;
                float v = acc[mt][nt][r];
                if (n < N1) {
                    v += b1[layer*N1 + n];
                    X1p[(size_t)m*N1 + n] = f2bf(v);
                } else {
                    v += b2[layer*HCH + (n - N1)];
                    X2p[(size_t)m*HCH + (n - N1)] = f2bf(v);
                }
            }
        }
    }
}

// ---------------------------------------------------------------- all-report barrier
// Zero atomic RMWs. Each WG stores its monotonically-increasing round number
// to its own flag slot; wave0's 64 lanes poll all 64 flags with one coalesced
// relaxed load + __all ballot. Per-layer gating:
//   L0 WG at round r:  flags[0..31] >= r           (L0 never reads L1 data)
//   L1 WG at round r:  flags[32..63] >= r  AND  flags[0..31] >= (r odd ? r : r-1)
// (odd r = 1+2s precedes phase A of step s, which reads y0seq[s] written by
//  L0's phase B of step s-1, completed when L0 flags reach 1+2s = r; even r
//  precedes phase B, which needs only y0seq[s] again => r-1.)
// Correctness: __syncthreads drains vmcnt(0) -> this WG's sc1 stores are at
// L3 before the flag store issues; flags monotonic; rounds < 2^32.
__device__ __forceinline__ void gbar2(unsigned int* flags, unsigned r, int layer) {
    __syncthreads();
    if (threadIdx.x < 64) {
        const unsigned lane = threadIdx.x;
        if (lane == blockIdx.x)
            __hip_atomic_store(&flags[lane*FLG_STRIDE], r, __ATOMIC_RELAXED,
                               __HIP_MEMORY_SCOPE_AGENT);
        const unsigned l0need = (r & 1u) ? r : (r - 1u);
        const unsigned need = (layer == 0) ? ((lane < 32u) ? r : 0u)
                                           : ((lane < 32u) ? l0need : r);
        for (;;) {
            unsigned v = __hip_atomic_load(&flags[lane*FLG_STRIDE],
                                           __ATOMIC_RELAXED, __HIP_MEMORY_SCOPE_AGENT);
            if (__all((int)(v >= need))) break;
            __builtin_amdgcn_s_sleep(1);
        }
    }
    __syncthreads();
}

// ---------------------------------------------------------------- fused recurrence
__global__ void __launch_bounds__(NTHR, 2)
rec_fused(const unsigned short* __restrict__ X1p,   // [32768][1024] bf16 (L0)
          const unsigned short* __restrict__ X2p,   // [32768][512]  bf16 (L0)
          const unsigned short* __restrict__ W1b,   // [L][1024][1024] bf16
          const unsigned short* __restrict__ W2b,   // [L][512][1024]  bf16
          const float* __restrict__ b1,
          const float* __restrict__ b2,
          const float* __restrict__ hiddens,        // [L][512]
          unsigned short* __restrict__ y0seq,       // [513][64][512] bf16
          unsigned short* __restrict__ h1b,         // [64][512] bf16
          unsigned short* __restrict__ rh0,         // [64][512] bf16
          unsigned short* __restrict__ rh1,         // [64][512] bf16
          float* __restrict__ out,                  // [512][64][512] f32
          float* __restrict__ hs,                   // [2][64][512]  f32
          unsigned int* __restrict__ flags) {
    __shared__ float zsh[BATCH*16];
    const int w     = blockIdx.x;
    const int tid   = threadIdx.x;
    const int lane  = tid & 63;
    const int v     = tid >> 6;
    const int rt    = v & 3;
    const int ct    = v >> 2;
    const int rfrag = lane & 15;
    const int quad  = lane >> 4;
    const int layer = (w >= 32) ? 1 : 0;
    const int c0    = (w & 31) * 16;
    const int arow  = rt*16 + rfrag;      // A-frag row (batch)
    const int crow  = rt*16 + quad*4;     // first owned C row
    const int ccol  = c0 + rfrag;         // owned col
    const int gcol  = (ct ? HCH : 0) + ccol;  // gate col in [0,1024)

    float hreg[4];
    #pragma unroll
    for (int r=0;r<4;++r) hreg[r] = hiddens[layer*HCH + ccol];
    const float bias1 = b1[(size_t)layer*N1 + gcol];   // used by L1 only
    const float bias2 = b2[(size_t)layer*HCH + ccol];  // used by L1 only

    // init h state (coherent pair-stores, even lanes carry (col, col+1))
    if (ct == 0) {
        unsigned short* dst = layer ? h1b : y0seq;     // y0seq slot 0
        #pragma unroll
        for (int r=0;r<4;++r) {
            unsigned short me = f2bf(hreg[r]);
            unsigned ot = (unsigned)__shfl_xor((int)(unsigned)me, 1, 64);
            if (!(lane & 1))
                st_word_co(&dst[(crow+r)*HCH + ccol], (unsigned)me | (ot << 16));
        }
    }
    unsigned rnd = 0;
    gbar2(flags, ++rnd, layer);

    for (int s = 0; s <= T_STEPS; ++s) {
        const int tt     = layer ? (s - 1) : s;           // this WG's timestep
        const int active = layer ? (s >= 1) : (s < T_STEPS);
        const unsigned short* aseq = y0seq + (size_t)s*BATCH*HCH;  // h0(t0-1) == y0(t1)

        // ---------------- phase A: gate pre-activations ----------------
        if (active) {
            floatx4 acc = (floatx4)(0.0f);
            const unsigned short* wrow = W1b + ((size_t)layer*N1 + gcol)*KCAT;
            if (!layer) {
                #pragma unroll
                for (int ks=0; ks<16; ++ks) {
                    bf16x8 a = ld_frag_co(&aseq[arow*HCH + ks*32 + quad*8]);
                    bf16x8 b = *reinterpret_cast<const bf16x8*>(&wrow[ICH + ks*32 + quad*8]);
                    acc = mfma_bf16(a, b, acc);
                }
            } else {
                #pragma unroll
                for (int ks=0; ks<16; ++ks) {           // k<512: y0(t1)
                    bf16x8 a = ld_frag_co(&aseq[arow*HCH + ks*32 + quad*8]);
                    bf16x8 b = *reinterpret_cast<const bf16x8*>(&wrow[ks*32 + quad*8]);
                    acc = mfma_bf16(a, b, acc);
                }
                #pragma unroll
                for (int ks=0; ks<16; ++ks) {           // k>=512: h1(t1-1)
                    bf16x8 a = ld_frag_co(&h1b[arow*HCH + ks*32 + quad*8]);
                    bf16x8 b = *reinterpret_cast<const bf16x8*>(&wrow[ICH + ks*32 + quad*8]);
                    acc = mfma_bf16(a, b, acc);
                }
            }
            float pre[4];
            if (!layer) {
                #pragma unroll
                for (int r=0;r<4;++r)
                    pre[r] = acc[r] + bf2f(X1p[(size_t)(tt*BATCH + crow + r)*N1 + gcol]);
            } else {
                #pragma unroll
                for (int r=0;r<4;++r) pre[r] = acc[r] + bias1;
            }
            if (ct == 0) {          // r-gate: rh = sigmoid(pre)*h  (h in regs)
                unsigned short* rbuf = layer ? rh1 : rh0;
                #pragma unroll
                for (int r=0;r<4;++r) {
                    float rh = sigmoidf_(pre[r]) * hreg[r];
                    unsigned short me = f2bf(rh);
                    unsigned ot = (unsigned)__shfl_xor((int)(unsigned)me, 1, 64);
                    if (!(lane & 1))
                        st_word_co(&rbuf[(crow+r)*HCH + ccol], (unsigned)me | (ot << 16));
                }
            } else {                // z-gate -> LDS
                #pragma unroll
                for (int r=0;r<4;++r)
                    zsh[(crow+r)*16 + rfrag] = sigmoidf_(pre[r]);
            }
        }
        gbar2(flags, ++rnd, layer);

        // ---------------- phase B: g = tanh(...), h update ----------------
        if (active && ct == 0) {
            floatx4 acc = (floatx4)(0.0f);
            const unsigned short* w2row = W2b + ((size_t)layer*HCH + ccol)*KCAT;
            const unsigned short* rbuf = layer ? rh1 : rh0;
            if (!layer) {
                #pragma unroll
                for (int ks=0; ks<16; ++ks) {
                    bf16x8 a = ld_frag_co(&rbuf[arow*HCH + ks*32 + quad*8]);
                    bf16x8 b = *reinterpret_cast<const bf16x8*>(&w2row[ICH + ks*32 + quad*8]);
                    acc = mfma_bf16(a, b, acc);
                }
            } else {
                #pragma unroll
                for (int ks=0; ks<16; ++ks) {           // k<512: y0(t1)
                    bf16x8 a = ld_frag_co(&aseq[arow*HCH + ks*32 + quad*8]);
                    bf16x8 b = *reinterpret_cast<const bf16x8*>(&w2row[ks*32 + quad*8]);
                    acc = mfma_bf16(a, b, acc);
                }
                #pragma unroll
                for (int ks=0; ks<16; ++ks) {           // k>=512: rh1
                    bf16x8 a = ld_frag_co(&rbuf[arow*HCH + ks*32 + quad*8]);
                    bf16x8 b = *reinterpret_cast<const bf16x8*>(&w2row[ICH + ks*32 + quad*8]);
                    acc = mfma_bf16(a, b, acc);
                }
            }
            unsigned short* hdst = layer ? h1b
                                         : (y0seq + (size_t)(tt+1)*BATCH*HCH);
            #pragma unroll
            for (int r=0;r<4;++r) {
                float x2 = layer ? bias2
                                 : bf2f(X2p[(size_t)(tt*BATCH + crow + r)*HCH + ccol]);
                float g  = tanhf(acc[r] + x2);
                float z  = zsh[(crow+r)*16 + rfrag];
                float hn = z*hreg[r] + (1.0f - z)*g;
                hreg[r] = hn;
                unsigned short me = f2bf(hn);
                unsigned ot = (unsigned)__shfl_xor((int)(unsigned)me, 1, 64);
                if (!(lane & 1))
                    st_word_co(&hdst[(crow+r)*HCH + ccol], (unsigned)me | (ot << 16));
                if (layer)
                    out[((size_t)tt*BATCH + crow + r)*HCH + ccol] = hn;
                if (tt == T_STEPS-1)
                    hs[(size_t)layer*BATCH*HCH + (crow+r)*HCH + ccol] = hn;
            }
        }
        gbar2(flags, ++rnd, layer);
    }
}

// ---------------------------------------------------------------- launch
extern "C" void kernel_launch(void* const* d_in, const int* in_sizes, int n_in,
                              void* d_out, int out_size, void* d_ws, size_t ws_size,
                              hipStream_t stream) {
    const float* x       = (const float*)d_in[0];
    const float* hiddens = (const float*)d_in[1];
    const float* W1      = (const float*)d_in[2];
    const float* b1      = (const float*)d_in[3];
    const float* W2      = (const float*)d_in[4];
    const float* b2      = (const float*)d_in[5];
    float* out = (float*)d_out;                    // [T][B][HC]
    float* hs  = out + (size_t)M_TOT*HCH;          // [L][B][HC]

    char* ws = (char*)d_ws;
    size_t off = 0;
    auto alloc = [&](size_t bytes) -> char* {
        char* p = ws + off; off += (bytes + 255) & ~(size_t)255; return p;
    };
    unsigned int*   flg   = (unsigned int*) alloc(4096);
    unsigned short* h1b   = (unsigned short*)alloc((size_t)BATCH*HCH*2);
    unsigned short* rh0   = (unsigned short*)alloc((size_t)BATCH*HCH*2);
    unsigned short* rh1   = (unsigned short*)alloc((size_t)BATCH*HCH*2);
    unsigned short* W1b   = (unsigned short*)alloc((size_t)NL*N1*KCAT*2);
    unsigned short* W2b   = (unsigned short*)alloc((size_t)NL*HCH*KCAT*2);
    unsigned short* xb    = (unsigned short*)alloc((size_t)M_TOT*ICH*2);
    unsigned short* X1p   = (unsigned short*)alloc((size_t)M_TOT*N1*2);
    unsigned short* X2p   = (unsigned short*)alloc((size_t)M_TOT*HCH*2);
    unsigned short* y0seq = (unsigned short*)alloc((size_t)(T_STEPS+1)*BATCH*HCH*2);

    hipMemsetAsync(flg, 0, 4096, stream);
    prep_kernel<<<2048, 256, 0, stream>>>(x, W1, W2, xb, W1b, W2b);
    xproj_kernel<<<dim3(12, 256), 256, 0, stream>>>(0, xb, W1b, W2b, b1, b2, X1p, X2p);
    rec_fused<<<NWG, NTHR, 0, stream>>>(X1p, X2p, W1b, W2b, b1, b2, hiddens,
        y0seq, h1b, rh0, rh1, out, hs, flg);
}